// Round 18
// baseline (23390.581 us; speedup 1.0000x reference)
//
// Round 18: the r17 TLP experiment, launched so it cannot be rejected.
// r17 post-mortem: absmax == max|ref| (2.828125) -> output all zeros ->
// hipLaunchCooperativeKernel REJECTED 512x1024 (needs exactly 2 blocks/CU,
// zero margin; error code was ignored). Fix: 512 WGs x 512 threads with
// __launch_bounds__(512,8) (VGPR<=64) -> capacity 4 blocks/CU, we use 2 ->
// 50% margin. Weight repack layout is flat in jtot so gates re-map to
// (row 200, half 2) = 400 threads, 2 K-halves (L1 30 / L2,L3 55 uint4 per
// thread) with NO repack change. CELL sums 2 partials; POLL = 175 parallel
// tasks (lid 337..511); everything else r15/r17-proven.

#include <hip/hip_runtime.h>
#include <hip/hip_cooperative_groups.h>

namespace cg = cooperative_groups;

#define HH 400
#define NK 10
#define VV 77
#define NO 121
#define TT 600
#define UU 64

#define NWG 512
#define NTH 512

#define KS  5      // repack slicing (layout only; flat in jtot)
#define J1  12
#define J23 22
#define JO  30
#define JH1  30    // L1 uint4 per K-half (60 total)
#define JH23 55    // L2/L3 uint4 per K-half (110 total)

// u32 offsets in ws (weight layout identical to r15..r17)
#define O_L1  0
#define O_L2  384000
#define O_L3  1088000
#define O_OUT 1792000
#define O_WW  1868800
#define O_XC  1874800    // exchange: 64 items x 600 u64

typedef _Float16 h2 __attribute__((ext_vector_type(2)));

struct Args {
  const float* __restrict__ x;
  const int*   __restrict__ text;
  const float* __restrict__ mask;
  const float* __restrict__ Wih1; const float* __restrict__ Whh1; const float* __restrict__ b1;
  const float* __restrict__ Wih2; const float* __restrict__ Whh2; const float* __restrict__ b2;
  const float* __restrict__ Wih3; const float* __restrict__ Whh3; const float* __restrict__ b3;
  const float* __restrict__ Wwin; const float* __restrict__ bwin;
  const float* __restrict__ Wout; const float* __restrict__ bout;
  float* __restrict__ out;
  float* __restrict__ ws;
};

__device__ __forceinline__ float sigm(float v) { return 1.0f / (1.0f + __expf(-v)); }

#if defined(__has_builtin)
#if __has_builtin(__builtin_amdgcn_fdot2)
#define FDOT2(a,b,c) __builtin_amdgcn_fdot2((a),(b),(c),false)
#endif
#endif
#ifndef FDOT2
#define FDOT2(a,b,c) fmaf((float)(a).x,(float)(b).x, fmaf((float)(a).y,(float)(b).y,(c)))
#endif

__device__ __forceinline__ h2 toh2(unsigned int u) { return __builtin_bit_cast(h2, u); }

__device__ __forceinline__ float dot4(uint4 p, uint4 v, float a) {
  a = FDOT2(toh2(p.x), toh2(v.x), a);
  a = FDOT2(toh2(p.y), toh2(v.y), a);
  a = FDOT2(toh2(p.z), toh2(v.z), a);
  a = FDOT2(toh2(p.w), toh2(v.w), a);
  return a;
}

__device__ __forceinline__ unsigned int packh2(float f0, float f1) {
  unsigned short lo = __builtin_bit_cast(unsigned short, (_Float16)f0);
  unsigned short hi = __builtin_bit_cast(unsigned short, (_Float16)f1);
  return (unsigned int)lo | ((unsigned int)hi << 16);
}

__global__ __launch_bounds__(512, 8) void hsnet_kernel(Args A) {
  cg::grid_group grid = cg::this_grid();
  const int lid  = threadIdx.x;
  const int bid  = blockIdx.x;
  const int band = bid & 7;        // one band per XCD
  const int item = bid >> 3;       // 0..63
  const int lane = lid & 63;
  const int wv   = lid >> 6;
  unsigned int* __restrict__ wsu = (unsigned int*)A.ws;

  // ===== prologue: weight repack (identical layout to r15) + zero exchange =====
  for (int i = bid * NTH + lid; i < O_XC; i += NWG * NTH) {
    float f0, f1;
    if (i < O_OUT) {
      const float *Wih, *Whh; int J, LD, rel;
      if (i < O_L2)      { rel = i;          J = J1;  LD = 80;  Wih = A.Wih1; Whh = A.Whh1; }
      else if (i < O_L3) { rel = i - O_L2;   J = J23; LD = 480; Wih = A.Wih2; Whh = A.Whh2; }
      else               { rel = i - O_L3;   J = J23; LD = 480; Wih = A.Wih3; Whh = A.Whh3; }
      int U = rel >> 2, c4 = rel & 3;
      int r = U % 200, T = U / 200;
      int j = T % J,  T2 = T / J;
      int s = T2 % KS, b = T2 / KS;
      int cell = b * 50 + (r % 50), gate = r / 50;
      int grow = gate * 400 + cell;
      int kk = (s * J + j) * 8 + 2 * c4;
      if (kk < LD) { f0 = Wih[grow * LD + kk];        f1 = Wih[grow * LD + kk + 1]; }
      else         { f0 = Whh[grow * 400 + kk - LD];  f1 = Whh[grow * 400 + kk - LD + 1]; }
    } else if (i < O_WW) {
      int rel = i - O_OUT;
      int U = rel >> 2, c4 = rel & 3;
      int o16 = U % 16, T = U / 16;
      int j = T % JO, T2 = T / JO;
      int s = T2 % KS, b = T2 / KS;
      int oglob = 8 * o16 + b;
      int kk = (s * JO + j) * 8 + 2 * c4;
      f0 = (oglob < NO) ? A.Wout[oglob * 1200 + kk]     : 0.f;
      f1 = (oglob < NO) ? A.Wout[oglob * 1200 + kk + 1] : 0.f;
    } else {
      int u = i - O_WW, ln = u / 100, p = u - ln * 100;
      int gw = ln >> 1, half = ln & 1, k0 = half * 200 + 2 * p;
      f0 = A.Wwin[gw * HH + k0]; f1 = A.Wwin[gw * HH + k0 + 1];
    }
    wsu[i] = packh2(f0, f1);
  }
  {
    unsigned long long* xz = (unsigned long long*)(wsu + O_XC);
    for (int i = bid * NTH + lid; i < 64 * 600; i += NWG * NTH)
      __hip_atomic_store(&xz[i], 0ull, __ATOMIC_RELAXED, __HIP_MEMORY_SCOPE_AGENT);
  }
  grid.sync();   // sole grid-wide event

  const uint4* W1b = (const uint4*)(wsu + O_L1)  + (size_t)band * KS * J1  * 200;
  const uint4* W2b = (const uint4*)(wsu + O_L2)  + (size_t)band * KS * J23 * 200;
  const uint4* W3b = (const uint4*)(wsu + O_L3)  + (size_t)band * KS * J23 * 200;
  const uint4* WOb = (const uint4*)(wsu + O_OUT) + (size_t)band * KS * JO  * 16;
  const unsigned int* __restrict__ WWIN = wsu + O_WW;
  unsigned long long* xg = (unsigned long long*)(wsu + O_XC) + (size_t)item * 600;

  __shared__ alignas(16) _Float16 svh1[480];   // [x3, w77, h1 400]
  __shared__ alignas(16) _Float16 svh2[880];   // [x3, h1, w77, h2]
  __shared__ alignas(16) _Float16 svh3[880];   // [x3, h2, w77, h3]
  __shared__ alignas(16) _Float16 soh[1200];   // [h1|h2|h3]
  __shared__ float pp[400];                    // [half 2][row 200]
  __shared__ float pO[80];                     // [s<5][oi 16]

  for (int i = lid; i < 480;  i += NTH) svh1[i] = (_Float16)0.f;
  for (int i = lid; i < 880;  i += NTH) { svh2[i] = (_Float16)0.f; svh3[i] = (_Float16)0.f; }
  for (int i = lid; i < 1200; i += NTH) soh[i] = (_Float16)0.f;
  __syncthreads();
  if (lid < 3) svh1[lid] = (_Float16)A.x[(size_t)item * TT * 3 + lid];

  const int rg = lid % 200;
  const int hg = lid / 200;   // K-half, active < 2
  float maskr = A.mask[item * UU + lane];
  int   textr = A.text[item * UU + lane];
  float bwinr = (lane < 60 && !(lane & 1)) ? A.bwin[lane >> 1] : 0.f;
  float kapr[NK];
  #pragma unroll
  for (int k = 0; k < NK; ++k) kapr[k] = 0.f;
  float2 c1 = {0.f, 0.f}, c2r = {0.f, 0.f}, c3r = {0.f, 0.f};
  __syncthreads();

// gate matvec: thread (rg, hg), K-half of JH uint4 each; layout flat in jtot
#define GATES(WB, JH)                                                         \
    if (hg < 2) {                                                             \
      const uint4* Wp = (WB) + (size_t)(hg * (JH)) * 200 + rg;                \
      float a0 = 0.f;                                                         \
      _Pragma("unroll 2")                                                     \
      for (int j = 0; j < (JH); ++j)                                          \
        a0 = dot4(Wp[(size_t)j * 200], vp0[hg * (JH) + j], a0);               \
      pp[hg * 200 + rg] = a0;                                                 \
    }

// cell update (lid<25): cells {2pr, 2pr+1}; publish tagged u64
#define CELL(B, CREG, PH, GEN, STORES)                                        \
    if (lid < 25) {                                                           \
      int pr = lid;                                                           \
      float2 hp;                                                              \
      _Pragma("unroll")                                                       \
      for (int e = 0; e < 2; ++e) {                                           \
        int cl = 2 * pr + e;                                                  \
        float gI = pp[cl]       + pp[200 + cl];                               \
        float gF = pp[50 + cl]  + pp[250 + cl];                               \
        float gG = pp[100 + cl] + pp[300 + cl];                               \
        float gO = pp[150 + cl] + pp[350 + cl];                               \
        int gcell = band * 50 + cl;                                           \
        gI += B[gcell]; gF += B[400 + gcell]; gG += B[800 + gcell]; gO += B[1200 + gcell]; \
        float cc = sigm(gF) * (e ? CREG.y : CREG.x) + sigm(gI) * tanhf(gG);   \
        if (e) CREG.y = cc; else CREG.x = cc;                                 \
        float h = sigm(gO) * tanhf(cc);                                       \
        if (e) hp.y = h; else hp.x = h;                                       \
      }                                                                       \
      h2 hh = { (_Float16)hp.x, (_Float16)hp.y };                             \
      int idx = band * 50 + 2 * pr;                                           \
      unsigned long long tw = ((unsigned long long)(GEN) << 32)               \
                            | (unsigned long long)__builtin_bit_cast(unsigned int, hh); \
      __hip_atomic_store(&xg[((PH) * 8 + band) * 25 + pr], tw,                \
                         __ATOMIC_RELAXED, __HIP_MEMORY_SCOPE_AGENT);         \
      STORES                                                                  \
    }

// poll peers: lid 337..511 = 175 parallel tasks (7 peers x 25 prs)
#define POLL(PH, GEN, DESTS)                                                  \
    if (lid >= 337) {                                                         \
      int task = lid - 337;                                                   \
      int p = task / 25, pr = task % 25;                                      \
      int pb = p + (p >= band);                                               \
      const unsigned int gexp = (GEN);                                        \
      unsigned long long v64;                                                 \
      while ((unsigned int)((v64 = __hip_atomic_load(                         \
                 &xg[((PH) * 8 + pb) * 25 + pr],                              \
                 __ATOMIC_RELAXED, __HIP_MEMORY_SCOPE_AGENT)) >> 32) != gexp) \
        __builtin_amdgcn_s_sleep(1);                                          \
      h2 hv = toh2((unsigned int)v64);                                        \
      int idx = pb * 50 + 2 * pr;                                             \
      DESTS                                                                   \
    }

  const uint4* vp0;

  for (int t = 0; t < TT; ++t) {
    // -- P1: out-write(t-1) + L1 gates --
    if (t > 0 && lid < 16) {
      int o = 8 * lid + band;
      if (o < NO) {
        float r = A.bout[o];
        #pragma unroll
        for (int s = 0; s < KS; ++s) r += pO[s * 16 + lid];
        A.out[((size_t)item * TT + (t - 1)) * NO + o] = r;
      }
    }
    vp0 = (const uint4*)svh1;
    GATES(W1b, JH1)
    __syncthreads();
    // -- P2: CELL1+publish + x(t) stage + POLL h1 --
    CELL(A.b1, c1, 0, 3u * t + 1u,
      soh[idx] = hh.x;       soh[idx + 1] = hh.y;
      svh1[80 + idx] = hh.x; svh1[81 + idx] = hh.y;
      svh2[3 + idx]  = hh.x; svh2[4 + idx]  = hh.y;
    )
    if (lid >= 32 && lid < 35) {
      int cm = lid - 32;
      _Float16 xv = (_Float16)A.x[((size_t)item * TT + t) * 3 + cm];
      svh2[cm] = xv; svh3[cm] = xv;
    }
    POLL(0, 3u * t + 1u,
      soh[idx] = hv.x;       soh[idx + 1] = hv.y;
      svh1[80 + idx] = hv.x; svh1[81 + idx] = hv.y;
      svh2[3 + idx]  = hv.x; svh2[4 + idx]  = hv.y;
    )
    __syncthreads();
    // -- P3: attention (wave 0) --
    if (wv == 0) {
      const h2* hO = (const h2*)soh;
      float m = 0.f;
      if (lane < 60) {
        const uint4* ww = (const uint4*)WWIN + lane * 25;
        const h2* hp = hO + (lane & 1) * 100;
        float acc = 0.f;
        #pragma unroll 5
        for (int p = 0; p < 25; ++p) {
          uint4 wq = ww[p];
          acc = FDOT2(toh2(wq.x), hp[4 * p + 0], acc);
          acc = FDOT2(toh2(wq.y), hp[4 * p + 1], acc);
          acc = FDOT2(toh2(wq.z), hp[4 * p + 2], acc);
          acc = FDOT2(toh2(wq.w), hp[4 * p + 3], acc);
        }
        m = acc;
      }
      m += __shfl_xor(m, 1);
      float mix = 0.f;
      if (lane < 60 && !(lane & 1)) mix = __expf(m + bwinr);
      float alpha[NK], beta[NK];
      #pragma unroll
      for (int k = 0; k < NK; ++k) {
        alpha[k] = __shfl(mix, 2 * k);
        beta[k]  = __shfl(mix, 20 + 2 * k);
        kapr[k] += __shfl(mix, 40 + 2 * k);
      }
      float u = (float)lane, phi = 0.f;
      #pragma unroll
      for (int k = 0; k < NK; ++k) {
        float d = kapr[k] - u;
        phi += alpha[k] * __expf(-beta[k] * d * d);
      }
      phi *= maskr;
      float w0a = 0.f, w1a = 0.f;
      #pragma unroll 8
      for (int uu2 = 0; uu2 < UU; ++uu2) {
        int   tu = __shfl(textr, uu2);
        float pu = __shfl(phi, uu2);
        w0a += (tu == lane)      ? pu : 0.f;
        w1a += (tu == lane + 64) ? pu : 0.f;
      }
      if (lane < VV) {
        _Float16 wh = (_Float16)w0a;
        svh1[3 + lane] = wh; svh2[403 + lane] = wh; svh3[403 + lane] = wh;
      }
      if (lane + 64 < VV) {
        _Float16 wh = (_Float16)w1a;
        svh1[67 + lane] = wh; svh2[467 + lane] = wh; svh3[467 + lane] = wh;
      }
    }
    __syncthreads();
    // -- P4: L2 gates --
    vp0 = (const uint4*)svh2;
    GATES(W2b, JH23)
    __syncthreads();
    // -- P5: CELL2+publish + POLL h2 --
    CELL(A.b2, c2r, 1, 3u * t + 2u,
      soh[400 + idx] = hh.x;  soh[401 + idx] = hh.y;
      svh2[480 + idx] = hh.x; svh2[481 + idx] = hh.y;
      svh3[3 + idx]   = hh.x; svh3[4 + idx]   = hh.y;
    )
    POLL(1, 3u * t + 2u,
      soh[400 + idx] = hv.x;  soh[401 + idx] = hv.y;
      svh2[480 + idx] = hv.x; svh2[481 + idx] = hv.y;
      svh3[3 + idx]   = hv.x; svh3[4 + idx]   = hv.y;
    )
    __syncthreads();
    // -- P6: L3 gates --
    vp0 = (const uint4*)svh3;
    GATES(W3b, JH23)
    __syncthreads();
    // -- P7: CELL3+publish + x(t+1) stage + out s<3 + POLL h3 --
    CELL(A.b3, c3r, 2, 3u * t + 3u,
      soh[800 + idx] = hh.x;  soh[801 + idx] = hh.y;
      svh3[480 + idx] = hh.x; svh3[481 + idx] = hh.y;
    )
    if (lid >= 32 && lid < 35 && t + 1 < TT) {
      int cm = lid - 32;
      svh1[cm] = (_Float16)A.x[((size_t)item * TT + (t + 1)) * 3 + cm];
    }
    if (lid >= 64 && lid < 112) {
      int oi = (lid - 64) & 15, s = (lid - 64) >> 4;   // s 0..2 (k<720: h1,h2)
      const uint4* Wp = WOb + (size_t)(s * JO) * 16 + oi;
      const uint4* p0 = (const uint4*)soh + s * JO;
      float a = 0.f;
      #pragma unroll 3
      for (int j = 0; j < JO; ++j)
        a = dot4(Wp[(size_t)j * 16], p0[j], a);
      pO[s * 16 + oi] = a;
    }
    POLL(2, 3u * t + 3u,
      soh[800 + idx] = hv.x;  soh[801 + idx] = hv.y;
      svh3[480 + idx] = hv.x; svh3[481 + idx] = hv.y;
    )
    __syncthreads();
    // -- P8: out s=3,4 (need h3) --
    if (lid < 32) {
      int oi = lid & 15, s = 3 + (lid >> 4);
      const uint4* Wp = WOb + (size_t)(s * JO) * 16 + oi;
      const uint4* p0 = (const uint4*)soh + s * JO;
      float a = 0.f;
      #pragma unroll 3
      for (int j = 0; j < JO; ++j)
        a = dot4(Wp[(size_t)j * 16], p0[j], a);
      pO[s * 16 + oi] = a;
    }
    __syncthreads();
  }
  // epilogue: out-write for t=599
  if (lid < 16) {
    int o = 8 * lid + band;
    if (o < NO) {
      float r = A.bout[o];
      #pragma unroll
      for (int s = 0; s < KS; ++s) r += pO[s * 16 + lid];
      A.out[((size_t)item * TT + (TT - 1)) * NO + o] = r;
    }
  }
#undef GATES
#undef CELL
#undef POLL
}

extern "C" void kernel_launch(void* const* d_in, const int* in_sizes, int n_in,
                              void* d_out, int out_size, void* d_ws, size_t ws_size,
                              hipStream_t stream) {
  Args a;
  a.x    = (const float*)d_in[0];
  a.text = (const int*)  d_in[1];
  a.mask = (const float*)d_in[2];
  a.Wih1 = (const float*)d_in[3];  a.Whh1 = (const float*)d_in[4];  a.b1 = (const float*)d_in[5];
  a.Wih2 = (const float*)d_in[6];  a.Whh2 = (const float*)d_in[7];  a.b2 = (const float*)d_in[8];
  a.Wih3 = (const float*)d_in[9];  a.Whh3 = (const float*)d_in[10]; a.b3 = (const float*)d_in[11];
  a.Wwin = (const float*)d_in[12]; a.bwin = (const float*)d_in[13];
  a.Wout = (const float*)d_in[14]; a.bout = (const float*)d_in[15];
  a.out  = (float*)d_out;
  a.ws   = (float*)d_ws;
  void* kargs[] = { &a };
  hipLaunchCooperativeKernel((const void*)hsnet_kernel, dim3(NWG), dim3(NTH),
                             kargs, 0, stream);
}

// Round 19
// 15658.672 us; speedup vs baseline: 1.4938x; 1.4938x over previous
//
// Round 19: r15 revert + single audited sync-diet edit (8 -> 7 syncs/step).
// r16 (sw overlap) and r17/r18 (TLP) all regressed vs r15's 16.48ms -> r15
// structure is the anchor. Only change: P8 eliminated. out s=3,4 for (t-1)
// (reads soh[720:1200), stable from P7(t-1) until P5(t)) moves to P2 on idle
// threads [448,480); out-write(t-1) moves to P3 on [128,160). POLL shifted to
// [64,414) so no poll task queues behind CELL. pO/soh hazards audited; all
// other code byte-identical to r15 (weights, exchange, band-per-XCD).

#include <hip/hip_runtime.h>
#include <hip/hip_cooperative_groups.h>

namespace cg = cooperative_groups;

#define HH 400
#define NK 10
#define VV 77
#define NO 121
#define TT 600
#define UU 64

#define NWG 256
#define NTH 1024

#define KS  5
#define J1  12
#define J23 22
#define JO  30

#define O_L1  0
#define O_L2  384000
#define O_L3  1088000
#define O_OUT 1792000
#define O_WW  1868800
#define O_XC  1874800

typedef _Float16 h2 __attribute__((ext_vector_type(2)));

struct Args {
  const float* __restrict__ x;
  const int*   __restrict__ text;
  const float* __restrict__ mask;
  const float* __restrict__ Wih1; const float* __restrict__ Whh1; const float* __restrict__ b1;
  const float* __restrict__ Wih2; const float* __restrict__ Whh2; const float* __restrict__ b2;
  const float* __restrict__ Wih3; const float* __restrict__ Whh3; const float* __restrict__ b3;
  const float* __restrict__ Wwin; const float* __restrict__ bwin;
  const float* __restrict__ Wout; const float* __restrict__ bout;
  float* __restrict__ out;
  float* __restrict__ ws;
};

__device__ __forceinline__ float sigm(float v) { return 1.0f / (1.0f + __expf(-v)); }

#if defined(__has_builtin)
#if __has_builtin(__builtin_amdgcn_fdot2)
#define FDOT2(a,b,c) __builtin_amdgcn_fdot2((a),(b),(c),false)
#endif
#endif
#ifndef FDOT2
#define FDOT2(a,b,c) fmaf((float)(a).x,(float)(b).x, fmaf((float)(a).y,(float)(b).y,(c)))
#endif

__device__ __forceinline__ h2 toh2(unsigned int u) { return __builtin_bit_cast(h2, u); }

__device__ __forceinline__ float dot4(uint4 p, uint4 v, float a) {
  a = FDOT2(toh2(p.x), toh2(v.x), a);
  a = FDOT2(toh2(p.y), toh2(v.y), a);
  a = FDOT2(toh2(p.z), toh2(v.z), a);
  a = FDOT2(toh2(p.w), toh2(v.w), a);
  return a;
}

__device__ __forceinline__ unsigned int packh2(float f0, float f1) {
  unsigned short lo = __builtin_bit_cast(unsigned short, (_Float16)f0);
  unsigned short hi = __builtin_bit_cast(unsigned short, (_Float16)f1);
  return (unsigned int)lo | ((unsigned int)hi << 16);
}

__global__ __launch_bounds__(1024) void hsnet_kernel(Args A) {
  cg::grid_group grid = cg::this_grid();
  const int lid  = threadIdx.x;
  const int bid  = blockIdx.x;
  const int band = bid & 7;
  const int grp  = bid >> 3;
  const int lane = lid & 63;
  const int wv   = lid >> 6;
  unsigned int* __restrict__ wsu = (unsigned int*)A.ws;

  // ===== prologue: weight repack + zero exchange (identical to r15) =====
  for (int i = bid * NTH + lid; i < O_XC; i += NWG * NTH) {
    float f0, f1;
    if (i < O_OUT) {
      const float *Wih, *Whh; int J, LD, rel;
      if (i < O_L2)      { rel = i;          J = J1;  LD = 80;  Wih = A.Wih1; Whh = A.Whh1; }
      else if (i < O_L3) { rel = i - O_L2;   J = J23; LD = 480; Wih = A.Wih2; Whh = A.Whh2; }
      else               { rel = i - O_L3;   J = J23; LD = 480; Wih = A.Wih3; Whh = A.Whh3; }
      int U = rel >> 2, c4 = rel & 3;
      int r = U % 200, T = U / 200;
      int j = T % J,  T2 = T / J;
      int s = T2 % KS, b = T2 / KS;
      int cell = b * 50 + (r % 50), gate = r / 50;
      int grow = gate * 400 + cell;
      int kk = (s * J + j) * 8 + 2 * c4;
      if (kk < LD) { f0 = Wih[grow * LD + kk];        f1 = Wih[grow * LD + kk + 1]; }
      else         { f0 = Whh[grow * 400 + kk - LD];  f1 = Whh[grow * 400 + kk - LD + 1]; }
    } else if (i < O_WW) {
      int rel = i - O_OUT;
      int U = rel >> 2, c4 = rel & 3;
      int o16 = U % 16, T = U / 16;
      int j = T % JO, T2 = T / JO;
      int s = T2 % KS, b = T2 / KS;
      int oglob = 8 * o16 + b;
      int kk = (s * JO + j) * 8 + 2 * c4;
      f0 = (oglob < NO) ? A.Wout[oglob * 1200 + kk]     : 0.f;
      f1 = (oglob < NO) ? A.Wout[oglob * 1200 + kk + 1] : 0.f;
    } else {
      int u = i - O_WW, ln = u / 100, p = u - ln * 100;
      int gw = ln >> 1, half = ln & 1, k0 = half * 200 + 2 * p;
      f0 = A.Wwin[gw * HH + k0]; f1 = A.Wwin[gw * HH + k0 + 1];
    }
    wsu[i] = packh2(f0, f1);
  }
  {
    unsigned long long* xz = (unsigned long long*)(wsu + O_XC);
    for (int i = bid * NTH + lid; i < 32 * 1200; i += NWG * NTH)
      __hip_atomic_store(&xz[i], 0ull, __ATOMIC_RELAXED, __HIP_MEMORY_SCOPE_AGENT);
  }
  grid.sync();

  const uint4* W1b = (const uint4*)(wsu + O_L1)  + (size_t)band * KS * J1  * 200;
  const uint4* W2b = (const uint4*)(wsu + O_L2)  + (size_t)band * KS * J23 * 200;
  const uint4* W3b = (const uint4*)(wsu + O_L3)  + (size_t)band * KS * J23 * 200;
  const uint4* WOb = (const uint4*)(wsu + O_OUT) + (size_t)band * KS * JO  * 16;
  const unsigned int* __restrict__ WWIN = wsu + O_WW;
  unsigned long long* xg = (unsigned long long*)(wsu + O_XC) + (size_t)grp * 1200;

  __shared__ alignas(16) _Float16 svh1[2][480];
  __shared__ alignas(16) _Float16 svh2[2][880];
  __shared__ alignas(16) _Float16 svh3[2][880];
  __shared__ alignas(16) _Float16 soh[2][1200];
  __shared__ float pp[2000];
  __shared__ float pO[160];

  for (int i = lid; i < 960;  i += NTH) (&svh1[0][0])[i] = (_Float16)0.f;
  for (int i = lid; i < 1760; i += NTH) { (&svh2[0][0])[i] = (_Float16)0.f;
                                          (&svh3[0][0])[i] = (_Float16)0.f; }
  for (int i = lid; i < 2400; i += NTH) (&soh[0][0])[i] = (_Float16)0.f;
  if (lid >= 512 && lid < 518) {
    int il = (lid - 512) / 3, cm = (lid - 512) % 3;
    svh1[il][cm] = (_Float16)A.x[(size_t)(2 * grp + il) * TT * 3 + cm];
  }

  const int rg = lid % 200;
  const int sg = lid / 200;
  const int itm = 2 * grp + ((wv < 2) ? wv : 0);
  float maskr = A.mask[itm * UU + lane];
  int   textr = A.text[itm * UU + lane];
  float bwinr = (lane < 60 && !(lane & 1)) ? A.bwin[lane >> 1] : 0.f;
  float kapr[NK];
  #pragma unroll
  for (int k = 0; k < NK; ++k) kapr[k] = 0.f;
  float2 c1 = {0.f, 0.f}, c2r = {0.f, 0.f}, c3r = {0.f, 0.f};
  __syncthreads();

#define GATES(WB, J, V0, V1)                                                  \
    if (sg < KS) {                                                            \
      const uint4* Wp = (WB) + (size_t)(sg * (J)) * 200 + rg;                 \
      const uint4* p0 = (const uint4*)((V0) + sg * (J) * 8);                  \
      const uint4* p1 = (const uint4*)((V1) + sg * (J) * 8);                  \
      float a0 = 0.f, a1 = 0.f;                                               \
      _Pragma("unroll 2")                                                     \
      for (int j = 0; j < (J); ++j) {                                         \
        uint4 w = Wp[(size_t)j * 200];                                        \
        a0 = dot4(w, p0[j], a0); a1 = dot4(w, p1[j], a1);                     \
      }                                                                       \
      pp[(sg * 2 + 0) * 200 + rg] = a0;                                       \
      pp[(sg * 2 + 1) * 200 + rg] = a1;                                       \
    }

#define CELL(B, CREG, PH, GEN, STORES)                                        \
    if (lid < 50) {                                                           \
      int il = lid / 25, pr = lid % 25;                                       \
      float2 hp;                                                              \
      _Pragma("unroll")                                                       \
      for (int e = 0; e < 2; ++e) {                                           \
        int cl = 2 * pr + e;                                                  \
        float gI = 0.f, gF = 0.f, gG = 0.f, gO = 0.f;                         \
        _Pragma("unroll")                                                     \
        for (int s = 0; s < KS; ++s) {                                        \
          const float* b0 = &pp[(s * 2 + il) * 200];                          \
          gI += b0[cl]; gF += b0[50 + cl]; gG += b0[100 + cl]; gO += b0[150 + cl]; \
        }                                                                     \
        int gcell = band * 50 + cl;                                           \
        gI += B[gcell]; gF += B[400 + gcell]; gG += B[800 + gcell]; gO += B[1200 + gcell]; \
        float cc = sigm(gF) * (e ? CREG.y : CREG.x) + sigm(gI) * tanhf(gG);   \
        if (e) CREG.y = cc; else CREG.x = cc;                                 \
        float h = sigm(gO) * tanhf(cc);                                       \
        if (e) hp.y = h; else hp.x = h;                                       \
      }                                                                       \
      h2 hh = { (_Float16)hp.x, (_Float16)hp.y };                             \
      int idx = band * 50 + 2 * pr;                                           \
      unsigned long long tw = ((unsigned long long)(GEN) << 32)               \
                            | (unsigned long long)__builtin_bit_cast(unsigned int, hh); \
      __hip_atomic_store(&xg[(((PH) * 8 + band) * 2 + il) * 25 + pr], tw,     \
                         __ATOMIC_RELAXED, __HIP_MEMORY_SCOPE_AGENT);         \
      STORES                                                                  \
    }

// poll 7 peer bands: lid in [64,414) -> 350 parallel tasks (no CELL overlap)
#define POLL(PH, GEN, DESTS)                                                  \
    if (lid >= 64 && lid < 414) {                                             \
      int task = lid - 64;                                                    \
      int p = task / 50, w = task % 50, il = w / 25, pr = w % 25;             \
      int pb = p + (p >= band);                                               \
      const unsigned int gexp = (GEN);                                        \
      unsigned long long v64;                                                 \
      while ((unsigned int)((v64 = __hip_atomic_load(                         \
                 &xg[(((PH) * 8 + pb) * 2 + il) * 25 + pr],                   \
                 __ATOMIC_RELAXED, __HIP_MEMORY_SCOPE_AGENT)) >> 32) != gexp) \
        __builtin_amdgcn_s_sleep(1);                                          \
      h2 hv = toh2((unsigned int)v64);                                        \
      int idx = pb * 50 + 2 * pr;                                             \
      DESTS                                                                   \
    }

// out-proj slices [S0,S1) on threads starting at LB (16 thr per slice; both items)
#define OUTS(S0, S1, LB)                                                      \
    if (lid >= (LB) && lid < (LB) + ((S1) - (S0)) * 16) {                     \
      int oi = (lid - (LB)) & 15, s = (S0) + ((lid - (LB)) >> 4);             \
      const uint4* Wp = WOb + (size_t)(s * JO) * 16 + oi;                     \
      const uint4* p0 = (const uint4*)(&soh[0][s * 240]);                     \
      const uint4* p1 = (const uint4*)(&soh[1][s * 240]);                     \
      float a0 = 0.f, a1 = 0.f;                                               \
      _Pragma("unroll 3")                                                     \
      for (int j = 0; j < JO; ++j) {                                          \
        uint4 w = Wp[(size_t)j * 16];                                         \
        a0 = dot4(w, p0[j], a0); a1 = dot4(w, p1[j], a1);                     \
      }                                                                       \
      pO[(s * 2 + 0) * 16 + oi] = a0;                                         \
      pO[(s * 2 + 1) * 16 + oi] = a1;                                         \
    }

  for (int t = 0; t < TT; ++t) {
    // -- P1: L1 gates (pure) --
    GATES(W1b, J1, svh1[0], svh1[1])
    __syncthreads();
    // -- P2: CELL1+publish || x(t) || out(t-1) s=3,4 || POLL h1 --
    CELL(A.b1, c1, 0, 3u * t + 1u,
      soh[il][idx] = hh.x;      soh[il][idx + 1] = hh.y;
      svh1[il][80 + idx] = hh.x; svh1[il][81 + idx] = hh.y;
      svh2[il][3 + idx]  = hh.x; svh2[il][4 + idx]  = hh.y;
    )
    if (lid >= 512 && lid < 518) {
      int il = (lid - 512) / 3, cm = (lid - 512) % 3;
      _Float16 xv = (_Float16)A.x[((size_t)(2 * grp + il) * TT + t) * 3 + cm];
      svh2[il][cm] = xv; svh3[il][cm] = xv;
    }
    if (t > 0) { OUTS(3, 5, 448) }   // reads soh[720:1200) = h2,h3 of t-1 (stable)
    POLL(0, 3u * t + 1u,
      soh[il][idx] = hv.x;      soh[il][idx + 1] = hv.y;
      svh1[il][80 + idx] = hv.x; svh1[il][81 + idx] = hv.y;
      svh2[il][3 + idx]  = hv.x; svh2[il][4 + idx]  = hv.y;
    )
    __syncthreads();
    // -- P3: attention (waves 0,1) || out-write(t-1) on [128,160) --
    if (wv < 2) {
      const int il = wv;
      const h2* hO = (const h2*)soh[il];
      float m = 0.f;
      if (lane < 60) {
        const uint4* ww = (const uint4*)WWIN + lane * 25;
        const h2* hp = hO + (lane & 1) * 100;
        float acc = 0.f;
        #pragma unroll 5
        for (int p = 0; p < 25; ++p) {
          uint4 wq = ww[p];
          acc = FDOT2(toh2(wq.x), hp[4 * p + 0], acc);
          acc = FDOT2(toh2(wq.y), hp[4 * p + 1], acc);
          acc = FDOT2(toh2(wq.z), hp[4 * p + 2], acc);
          acc = FDOT2(toh2(wq.w), hp[4 * p + 3], acc);
        }
        m = acc;
      }
      m += __shfl_xor(m, 1);
      float mix = 0.f;
      if (lane < 60 && !(lane & 1)) mix = __expf(m + bwinr);
      float alpha[NK], beta[NK];
      #pragma unroll
      for (int k = 0; k < NK; ++k) {
        alpha[k] = __shfl(mix, 2 * k);
        beta[k]  = __shfl(mix, 20 + 2 * k);
        kapr[k] += __shfl(mix, 40 + 2 * k);
      }
      float u = (float)lane, phi = 0.f;
      #pragma unroll
      for (int k = 0; k < NK; ++k) {
        float d = kapr[k] - u;
        phi += alpha[k] * __expf(-beta[k] * d * d);
      }
      phi *= maskr;
      float w0a = 0.f, w1a = 0.f;
      #pragma unroll 8
      for (int uu2 = 0; uu2 < UU; ++uu2) {
        int   tu = __shfl(textr, uu2);
        float pu = __shfl(phi, uu2);
        w0a += (tu == lane)      ? pu : 0.f;
        w1a += (tu == lane + 64) ? pu : 0.f;
      }
      if (lane < VV) {
        _Float16 wh = (_Float16)w0a;
        svh1[il][3 + lane] = wh; svh2[il][403 + lane] = wh; svh3[il][403 + lane] = wh;
      }
      if (lane + 64 < VV) {
        _Float16 wh = (_Float16)w1a;
        svh1[il][67 + lane] = wh; svh2[il][467 + lane] = wh; svh3[il][467 + lane] = wh;
      }
    }
    if (t > 0 && lid >= 128 && lid < 160) {
      int k2 = lid - 128, oi = k2 & 15, il = k2 >> 4;
      int o = 8 * oi + band;
      if (o < NO) {
        float r = A.bout[o];
        #pragma unroll
        for (int s = 0; s < KS; ++s) r += pO[(s * 2 + il) * 16 + oi];
        A.out[((size_t)(2 * grp + il) * TT + (t - 1)) * NO + o] = r;
      }
    }
    __syncthreads();
    // -- P4: L2 gates --
    GATES(W2b, J23, svh2[0], svh2[1])
    __syncthreads();
    // -- P5: CELL2+publish || POLL h2 --
    CELL(A.b2, c2r, 1, 3u * t + 2u,
      soh[il][400 + idx] = hh.x;  soh[il][401 + idx] = hh.y;
      svh2[il][480 + idx] = hh.x; svh2[il][481 + idx] = hh.y;
      svh3[il][3 + idx]   = hh.x; svh3[il][4 + idx]   = hh.y;
    )
    POLL(1, 3u * t + 2u,
      soh[il][400 + idx] = hv.x;  soh[il][401 + idx] = hv.y;
      svh2[il][480 + idx] = hv.x; svh2[il][481 + idx] = hv.y;
      svh3[il][3 + idx]   = hv.x; svh3[il][4 + idx]   = hv.y;
    )
    __syncthreads();
    // -- P6: L3 gates --
    GATES(W3b, J23, svh3[0], svh3[1])
    __syncthreads();
    // -- P7: CELL3+publish || x(t+1) || out(t) s<3 (h1,h2) || POLL h3 --
    CELL(A.b3, c3r, 2, 3u * t + 3u,
      soh[il][800 + idx] = hh.x;  soh[il][801 + idx] = hh.y;
      svh3[il][480 + idx] = hh.x; svh3[il][481 + idx] = hh.y;
    )
    if (lid >= 512 && lid < 518 && t + 1 < TT) {
      int il = (lid - 512) / 3, cm = (lid - 512) % 3;
      svh1[il][cm] = (_Float16)A.x[((size_t)(2 * grp + il) * TT + (t + 1)) * 3 + cm];
    }
    OUTS(0, 3, 448)   // reads soh[0:720) = h1(t),h2(t) (synced at P2/P5)
    POLL(2, 3u * t + 3u,
      soh[il][800 + idx] = hv.x;  soh[il][801 + idx] = hv.y;
      svh3[il][480 + idx] = hv.x; svh3[il][481 + idx] = hv.y;
    )
    __syncthreads();
  }
  // epilogue: out(599) s=3,4 then write
  OUTS(3, 5, 448)
  __syncthreads();
  if (lid < 32) {
    int oi = lid & 15, il = lid >> 4;
    int o = 8 * oi + band;
    if (o < NO) {
      float r = A.bout[o];
      #pragma unroll
      for (int s = 0; s < KS; ++s) r += pO[(s * 2 + il) * 16 + oi];
      A.out[((size_t)(2 * grp + il) * TT + (TT - 1)) * NO + o] = r;
    }
  }
#undef GATES
#undef CELL
#undef POLL
#undef OUTS
}

extern "C" void kernel_launch(void* const* d_in, const int* in_sizes, int n_in,
                              void* d_out, int out_size, void* d_ws, size_t ws_size,
                              hipStream_t stream) {
  Args a;
  a.x    = (const float*)d_in[0];
  a.text = (const int*)  d_in[1];
  a.mask = (const float*)d_in[2];
  a.Wih1 = (const float*)d_in[3];  a.Whh1 = (const float*)d_in[4];  a.b1 = (const float*)d_in[5];
  a.Wih2 = (const float*)d_in[6];  a.Whh2 = (const float*)d_in[7];  a.b2 = (const float*)d_in[8];
  a.Wih3 = (const float*)d_in[9];  a.Whh3 = (const float*)d_in[10]; a.b3 = (const float*)d_in[11];
  a.Wwin = (const float*)d_in[12]; a.bwin = (const float*)d_in[13];
  a.Wout = (const float*)d_in[14]; a.bout = (const float*)d_in[15];
  a.out  = (float*)d_out;
  a.ws   = (float*)d_ws;
  void* kargs[] = { &a };
  hipLaunchCooperativeKernel((const void*)hsnet_kernel, dim3(NWG), dim3(NTH),
                             kargs, 0, stream);
}